// Round 2
// 371.838 us; speedup vs baseline: 1.0189x; 1.0189x over previous
//
#include <hip/hip_runtime.h>

// Problem: x (32, 2, 24, 32768) f32 -> out (32, 2, 30, 32768) f32
// out[b,c,t,l] = mean over the 3 channels of triangle t.
// HBM-bound: ideal traffic = 201.3 MB read + 251.7 MB write = 453 MB -> ~72 us
// at 6.3 TB/s. Rolling-window schedule: channel c is loaded 6 triangles before
// its first use (compile-time LOAD_AT table), so the live set is ~10 vec4
// instead of 24 and stores retire per-triangle.

#define L_DIM   32768
#define L4_DIM  (L_DIM / 4)   // 8192 vec4 per channel row
#define NCH     24
#define NTRI    30
#define BLOCK   256

// Native clang vector type: __builtin_nontemporal_load/store require a
// vector-of-float pointer (HIP's float4 is a class and is rejected).
typedef float f32x4 __attribute__((ext_vector_type(4)));

// Triangle table (compile-time so the t-loop folds to register adds).
constexpr int TA[NTRI] = {0,0,1,1,2,3,4,4,5,5,7,7,8,8,9,10,11,11,12,12,14,14,15,15,16,17,18,18,19,19};
constexpr int TB[NTRI] = {3,1,4,2,5,4,7,5,8,6,10,8,11,9,12,11,14,12,15,13,17,15,18,16,19,18,21,19,22,20};
constexpr int TC[NTRI] = {4,4,5,5,6,7,8,8,9,9,11,11,12,12,13,14,15,15,16,16,18,18,19,19,20,21,22,22,23,23};

// LOAD_AT[c] = max(0, first_use_triangle(c) - 6): issue the global load for
// channel c just before computing triangle LOAD_AT[c]. TC is non-decreasing,
// so every channel is in registers >=6 triangles before first use, and dead
// ~8 triangles later. All compile-time constants -> the if below constant-
// folds; v[] is only ever indexed by constants (stays in registers).
constexpr int LOAD_AT[NCH] = {
    0, 0, 0, 0, 0, 0, 0, 0, 0,   // ch 0-8 (first uses t=0..6)
    2,                            // ch 9  (first use t=8)
    4, 4,                         // ch 10,11 (t=10)
    6,                            // ch 12 (t=12)
    8,                            // ch 13 (t=14)
    9,                            // ch 14 (t=15)
    10,                           // ch 15 (t=16)
    12,                           // ch 16 (t=18)
    14, 14,                       // ch 17,18 (t=20)
    16,                           // ch 19 (t=22)
    18,                           // ch 20 (t=24)
    19,                           // ch 21 (t=25)
    20,                           // ch 22 (t=26)
    22                            // ch 23 (t=28)
};

// __launch_bounds__(256, 4): 4 waves/EU min -> VGPR cap 128. Live set here is
// ~40-60 VGPRs of data + addressing, so this is safe and roughly doubles
// occupancy vs the 129-256 VGPR band of the 24-upfront-loads version.
__global__ __launch_bounds__(BLOCK, 4) void tri_mean_kernel(
    const float* __restrict__ x, float* __restrict__ out)
{
    const int l4 = blockIdx.x * BLOCK + threadIdx.x;   // vec4 index in [0, L4_DIM)
    const int bc = blockIdx.y;                          // (b*2 + c) in [0, 64)

    const f32x4* __restrict__ xin = (const f32x4*)(x + (size_t)bc * NCH * L_DIM);
    f32x4* __restrict__ o = (f32x4*)(out + (size_t)bc * NTRI * L_DIM);

    f32x4 v[NCH];
    const float k = 1.0f / 3.0f;

#pragma unroll
    for (int t = 0; t < NTRI; ++t) {
        // Issue this step's channel loads (nontemporal: data is read exactly
        // once across the whole grid; keep it out of L2/MALL).
#pragma unroll
        for (int c = 0; c < NCH; ++c) {
            if (LOAD_AT[c] == t) {
                v[c] = __builtin_nontemporal_load(&xin[(size_t)c * L4_DIM + l4]);
            }
        }

        const f32x4 a = v[TA[t]];
        const f32x4 b = v[TB[t]];
        const f32x4 c = v[TC[t]];
        f32x4 r = (a + b + c) * k;
        __builtin_nontemporal_store(r, &o[(size_t)t * L4_DIM + l4]);
    }
}

extern "C" void kernel_launch(void* const* d_in, const int* in_sizes, int n_in,
                              void* d_out, int out_size, void* d_ws, size_t ws_size,
                              hipStream_t stream) {
    const float* x = (const float*)d_in[0];
    float* out = (float*)d_out;

    dim3 block(BLOCK);
    dim3 grid(L4_DIM / BLOCK, 64);  // 32 x 64 = 2048 blocks
    tri_mean_kernel<<<grid, block, 0, stream>>>(x, out);
}